// Round 3
// baseline (846.949 us; speedup 1.0000x reference)
//
#include <hip/hip_runtime.h>
#include <hip/hip_bf16.h>
#include <math.h>

typedef __attribute__((ext_vector_type(8))) short   short8;
typedef __attribute__((ext_vector_type(4))) float   floatx4;

// ---------------- workspace layout (bytes) ----------------
#define OFF_PRED     0ULL          // 32*18*4
#define OFF_PTA      16384ULL
#define OFF_PTB      65536ULL
#define OFF_W2B      131072ULL     // 3 * 524288 (bf16, same (1024,256) layout)
#define OFF_X        16777216ULL   // 12845056 B bf16
#define OFF_P1       33554432ULL   // 28*256*1024*4 = 29360128 B
#define OFF_W1T      67108864ULL   // 89915392 B (3 levels)

// ---------------- pair-gather helpers ----------------
__device__ inline void pair_idx(int p, int Pn, int npnt, int& i1, int& i2) {
    if (p == 0) { i1 = i2 = 0; }
    else if (p >= Pn - 2) { i1 = i2 = npnt - (Pn - p); }
    else {
        int q = (p - 1) >> 1, r = (p - 1) & 1;
        int si = 1 + 3 * q;
        if (r == 0) { i1 = i2 = si; } else { i1 = si + 1; i2 = si + 2; }
    }
}
__device__ inline float2 pred_point(const float* pred0, const float* pt,
                                    int nsegP, int b, int p) {
    if (nsegP == 0) {
        const float* q = pred0 + ((size_t)b * 9 + p) * 2;
        return float2{q[0], q[1]};
    }
    int npnt = nsegP * 3, Pn = 2 * nsegP + 1;
    int i1, i2; pair_idx(p, Pn, npnt, i1, i2);
    const float* a = pt + ((size_t)b * npnt + i1) * 2;
    const float* c = pt + ((size_t)b * npnt + i2) * 2;
    return float2{0.5f * (a[0] + c[0]), 0.5f * (a[1] + c[1])};
}

// ---------------- fused setup ----------------
struct SetupArgs {
    const float* W1s[3]; __hip_bfloat16* W1T[3]; int K[3];
    const float* W2s[3]; __hip_bfloat16* W2B[3];
    const float* lf; const float* Wt; const float* bt; float* pred;
};

// grid: [0,10976) W1 64x64 transpose tiles | [10976,11744) W2 convert | [11744,11888) pred
__global__ __launch_bounds__(256) void setup_kernel(SetupArgs a) {
    __shared__ float tile[64][65];
    int id = blockIdx.x;
    int t = threadIdx.x;
    if (id < 10976) {
        int h, base;
        if (id < 6272) { h = 0; base = 0; }
        else if (id < 9408) { h = 1; base = 6272; }
        else { h = 2; base = 9408; }
        int l = id - base;
        int K = a.K[h];
        const float* src = a.W1s[h];
        __hip_bfloat16* dst = a.W1T[h];
        int r0 = (l >> 4) * 64, c0 = (l & 15) * 64;   // r0: k-dim, c0: n-dim
        int col = t & 63, row4 = t >> 6;
        #pragma unroll
        for (int g = 0; g < 16; ++g)
            tile[row4 + g * 4][col] =
                src[(size_t)(r0 + row4 + g * 4) * 1024 + c0 + col];
        __syncthreads();
        int ox = t & 31, oy = t >> 5;
        #pragma unroll
        for (int g = 0; g < 8; ++g) {
            int n = oy + g * 8;
            __hip_bfloat16 h0 = __float2bfloat16(tile[ox * 2][n]);
            __hip_bfloat16 h1 = __float2bfloat16(tile[ox * 2 + 1][n]);
            ushort2 u = {*(unsigned short*)&h0, *(unsigned short*)&h1};
            *(ushort2*)((unsigned short*)dst + (size_t)(c0 + n) * K + r0 + ox * 2) = u;
        }
    } else if (id < 11744) {
        int l = id - 10976;
        int h = l >> 8, blk = l & 255;
        int idx = blk * 1024 + t * 4;
        float4 v = *(const float4*)(a.W2s[h] + idx);
        __hip_bfloat16 h0 = __float2bfloat16(v.x), h1 = __float2bfloat16(v.y);
        __hip_bfloat16 h2 = __float2bfloat16(v.z), h3 = __float2bfloat16(v.w);
        ushort4 u = {*(unsigned short*)&h0, *(unsigned short*)&h1,
                     *(unsigned short*)&h2, *(unsigned short*)&h3};
        *(ushort4*)((unsigned short*)a.W2B[h] + idx) = u;
    } else {
        int l = id - 11744;
        int wave = t >> 6, lane = t & 63;
        int task = l * 4 + wave;         // < 576
        int j = task % 18, b = task / 18;
        const float* lfb = a.lf + (size_t)b * 4096;
        float acc = 0.f;
        for (int k = lane; k < 4096; k += 64)
            acc += lfb[k] * a.Wt[(size_t)k * 18 + j];
        #pragma unroll
        for (int off = 32; off >= 1; off >>= 1)
            acc += __shfl_xor(acc, off, 64);
        if (lane == 0) a.pred[b * 18 + j] = acc + a.bt[j];
    }
}

// ---------------- bilinear ROI sampling ----------------
__global__ __launch_bounds__(256) void sample_kernel(
    const float* __restrict__ feat, int Wd, int lc,
    const float* __restrict__ pred0, const float* __restrict__ ptPrev, int nsegP,
    int lns, __hip_bfloat16* __restrict__ x)
{
    int nseg = 1 << lns;
    int blk = blockIdx.x;
    int i = blk & (nseg - 1), b = blk >> lns;
    float2 p0 = pred_point(pred0, ptPrev, nsegP, b, i);
    float2 p1 = pred_point(pred0, ptPrev, nsegP, b, i + 1);
    float cx = 0.5f * (p0.x + p1.x), cy = 0.5f * (p0.y + p1.y);
    float dx = 0.5f * (p1.x - p0.x), dy = 0.5f * (p1.y - p0.y);

    __shared__ float4 wv[49];
    __shared__ int4   ov[49];
    int t = threadIdx.x;
    int C = 1 << lc;
    if (t < 49) {
        int oy = t / 7, ox = t - oy * 7;
        float gx = (float)(ox - 3) * (1.f / 3.f);
        float gy = (float)(oy - 3) * (1.f / 3.f);
        float xs = dx * gx - dy * gy - cx;
        float ys = dy * gx + dx * gy - cy;
        float fW = (float)(Wd - 1);
        float px = (xs + 1.f) * fW * 0.5f;
        float py = (ys + 1.f) * fW * 0.5f;
        float x0f = floorf(px), y0f = floorf(py);
        float wx = px - x0f, wy = py - y0f;
        int xi0 = (int)fminf(fmaxf(x0f,       0.f), fW);
        int xi1 = (int)fminf(fmaxf(x0f + 1.f, 0.f), fW);
        int yi0 = (int)fminf(fmaxf(y0f,       0.f), fW);
        int yi1 = (int)fminf(fmaxf(y0f + 1.f, 0.f), fW);
        int c4 = C >> 2;
        ov[t] = int4{(yi0 * Wd + xi0) * c4, (yi1 * Wd + xi0) * c4,
                     (yi0 * Wd + xi1) * c4, (yi1 * Wd + xi1) * c4};
        wv[t] = float4{(1.f - wx) * (1.f - wy), (1.f - wx) * wy,
                       wx * (1.f - wy),         wx * wy};
    }
    __syncthreads();

    const float4* fb4 = (const float4*)(feat + (size_t)b * Wd * Wd * C);
    int c4 = 1 << (lc - 2);
    int total4 = 49 << (lc - 2);
    size_t rowbase = (size_t)blk * (49 << lc);
    for (int j = t; j < total4; j += 256) {
        int pix = j >> (lc - 2);
        int cc  = j & (c4 - 1);
        int4 o = ov[pix]; float4 w = wv[pix];
        float4 Ia = fb4[o.x + cc], Ib = fb4[o.y + cc];
        float4 Ic = fb4[o.z + cc], Id = fb4[o.w + cc];
        float4 v;
        v.x = w.x * Ia.x + w.y * Ib.x + w.z * Ic.x + w.w * Id.x;
        v.y = w.x * Ia.y + w.y * Ib.y + w.z * Ic.y + w.w * Id.y;
        v.z = w.x * Ia.z + w.y * Ib.z + w.z * Ic.z + w.w * Id.z;
        v.w = w.x * Ia.w + w.y * Ib.w + w.z * Ic.w + w.w * Id.w;
        __hip_bfloat16 h0 = __float2bfloat16(v.x), h1 = __float2bfloat16(v.y);
        __hip_bfloat16 h2 = __float2bfloat16(v.z), h3 = __float2bfloat16(v.w);
        ushort4 u = {*(unsigned short*)&h0, *(unsigned short*)&h1,
                     *(unsigned short*)&h2, *(unsigned short*)&h3};
        *(ushort4*)(x + rowbase + ((size_t)pix << lc) + cc * 4) = u;
    }
}

// ---------------- bf16 MFMA GEMM, split-K, 4 waves/block ----------------
__global__ __launch_bounds__(256) void gemm_mfma4(
    const __hip_bfloat16* __restrict__ A, const __hip_bfloat16* __restrict__ Bt,
    float* __restrict__ P, int M, int N, int K, int slice)
{
    int lane = threadIdx.x & 63;
    int wave = threadIdx.x >> 6;
    int lo = lane & 15, hi = lane >> 4;
    int mt = blockIdx.x, nt = blockIdx.y * 4 + wave, s = blockIdx.z;
    const short* Ap = (const short*)A + (size_t)(mt * 64 + lo) * K + (size_t)s * slice + hi * 8;
    const short* Bp = (const short*)Bt + (size_t)(nt * 64 + lo) * K + (size_t)s * slice + hi * 8;

    floatx4 acc[4][4];
    #pragma unroll
    for (int a = 0; a < 4; ++a)
        #pragma unroll
        for (int b = 0; b < 4; ++b)
            acc[a][b] = floatx4{0.f, 0.f, 0.f, 0.f};

    short8 ca[4], cb[4], na[4], nb[4];
    int nch = slice >> 5;

#define LDF(da, db, koff)                                                     \
    {                                                                         \
        _Pragma("unroll")                                                     \
        for (int q = 0; q < 4; ++q)                                           \
            da[q] = *(const short8*)(Ap + (size_t)q * 16 * K + (koff));       \
        _Pragma("unroll")                                                     \
        for (int q = 0; q < 4; ++q)                                           \
            db[q] = *(const short8*)(Bp + (size_t)q * 16 * K + (koff));       \
    }
#define MM(da, db)                                                            \
    {                                                                         \
        _Pragma("unroll")                                                     \
        for (int mi = 0; mi < 4; ++mi)                                        \
            _Pragma("unroll")                                                 \
            for (int ni = 0; ni < 4; ++ni)                                    \
                acc[mi][ni] = __builtin_amdgcn_mfma_f32_16x16x32_bf16(        \
                    da[mi], db[ni], acc[mi][ni], 0, 0, 0);                    \
    }

    LDF(ca, cb, 0)
    for (int c = 0; c + 1 < nch; c += 2) {
        LDF(na, nb, (c + 1) * 32)
        MM(ca, cb)
        if (c + 2 < nch) LDF(ca, cb, (c + 2) * 32)
        MM(na, nb)
    }
    if (nch & 1) MM(ca, cb)

    #pragma unroll
    for (int mi = 0; mi < 4; ++mi) {
        int row0 = mt * 64 + mi * 16 + hi * 4;
        #pragma unroll
        for (int ni = 0; ni < 4; ++ni) {
            int col = nt * 64 + ni * 16 + lo;
            #pragma unroll
            for (int r = 0; r < 4; ++r)
                P[((size_t)s * M + row0 + r) * N + col] = acc[mi][ni][r];
        }
    }
#undef LDF
#undef MM
}

// ---------------- fused tail: reduce+tanh -> f2=f1@W2 -> tanh -> @W3 -> theta -> pt ----
// one block per 4 output rows (m0..m0+3)
__global__ __launch_bounds__(256) void tail_kernel(
    const float* __restrict__ P1, const float* __restrict__ b1,
    const __hip_bfloat16* __restrict__ W2B, const float* __restrict__ b2,
    const float* __restrict__ W3, const float* __restrict__ b3,
    const float* __restrict__ pred0, const float* __restrict__ ptPrev, int nsegP,
    float* __restrict__ pt, int lns, int M, int S)
{
    __shared__ float f1s[4 * 1024];     // phase1: [m][j]; phase2b: partials
    __shared__ float red[4][24];
    __shared__ float fin[24];
    int t = threadIdx.x;
    int m0 = blockIdx.x * 4;

    // phase 1: f1[m][:] = tanh(b1 + sum_s P1[s][m][:])
    float4 bv = ((const float4*)b1)[t];
    #pragma unroll
    for (int q = 0; q < 4; ++q) {
        float4 v = bv;
        for (int s = 0; s < S; ++s) {
            float4 p = ((const float4*)(P1 + ((size_t)s * M + m0 + q) * 1024))[t];
            v.x += p.x; v.y += p.y; v.z += p.z; v.w += p.w;
        }
        float4 o = {tanhf(v.x), tanhf(v.y), tanhf(v.z), tanhf(v.w)};
        ((float4*)(f1s + q * 1024))[t] = o;
    }
    __syncthreads();

    // phase 2: f2 partials; thread (jq = t>>6, kq = t&63) covers k = kq*4..+3
    int kq = t & 63, jq = t >> 6;
    float acc[4][4];
    #pragma unroll
    for (int q = 0; q < 4; ++q)
        #pragma unroll
        for (int r = 0; r < 4; ++r) acc[q][r] = 0.f;
    for (int j = jq * 256; j < jq * 256 + 256; ++j) {
        ushort4 w = *(const ushort4*)((const unsigned short*)W2B + (size_t)j * 256 + kq * 4);
        float w0 = __uint_as_float((unsigned)w.x << 16);
        float w1 = __uint_as_float((unsigned)w.y << 16);
        float w2 = __uint_as_float((unsigned)w.z << 16);
        float w3 = __uint_as_float((unsigned)w.w << 16);
        #pragma unroll
        for (int q = 0; q < 4; ++q) {
            float f = f1s[q * 1024 + j];
            acc[q][0] += f * w0; acc[q][1] += f * w1;
            acc[q][2] += f * w2; acc[q][3] += f * w3;
        }
    }
    __syncthreads();
    #pragma unroll
    for (int q = 0; q < 4; ++q)
        ((float4*)f1s)[(jq * 64 + kq) * 4 + q] =
            float4{acc[q][0], acc[q][1], acc[q][2], acc[q][3]};
    __syncthreads();

    // combine over jq; thread t = k
    int kq2 = t >> 2, ks = t & 3;
    float vv[4];
    float bb = b2[t];
    #pragma unroll
    for (int q = 0; q < 4; ++q) {
        float s4 = 0.f;
        #pragma unroll
        for (int j2 = 0; j2 < 4; ++j2)
            s4 += f1s[((j2 * 64 + kq2) * 4 + q) * 4 + ks];
        vv[q] = tanhf(s4 + bb);
    }

    // W3 stage: a[q][j] = sum_k vv[q][k] * W3[k][j]
    float w6[6];
    #pragma unroll
    for (int j = 0; j < 6; ++j) w6[j] = W3[t * 6 + j];
    float a[24];
    #pragma unroll
    for (int q = 0; q < 4; ++q)
        #pragma unroll
        for (int j = 0; j < 6; ++j) a[q * 6 + j] = vv[q] * w6[j];
    #pragma unroll
    for (int off = 32; off >= 1; off >>= 1)
        #pragma unroll
        for (int e = 0; e < 24; ++e) a[e] += __shfl_xor(a[e], off, 64);
    int wave = t >> 6, lane = t & 63;
    if (lane == 0) {
        #pragma unroll
        for (int e = 0; e < 24; ++e) red[wave][e] = a[e];
    }
    __syncthreads();
    if (t < 24) fin[t] = red[0][t] + red[1][t] + red[2][t] + red[3][t];
    __syncthreads();
    if (t < 4) {
        int m = m0 + t;
        int nseg = 1 << lns;
        int i = m & (nseg - 1), b = m >> lns;
        float2 p0 = pred_point(pred0, ptPrev, nsegP, b, i);
        float2 p1 = pred_point(pred0, ptPrev, nsegP, b, i + 1);
        float cx = 0.5f * (p0.x + p1.x), cy = 0.5f * (p0.y + p1.y);
        float dx = 0.5f * (p1.x - p0.x), dy = 0.5f * (p1.y - p0.y);
        float f[6];
        #pragma unroll
        for (int j = 0; j < 6; ++j) f[j] = fin[t * 6 + j] + b3[j];
        f[0] -= 1.f;
        f[4] += 1.f;
        int npnt = nseg * 3;
        size_t base = ((size_t)b * npnt + 3 * i) * 2;
        #pragma unroll
        for (int s = 0; s < 3; ++s) {
            float px = f[2 * s], py = f[2 * s + 1];
            pt[base + 2 * s]     = dx * px - dy * py + cx;
            pt[base + 2 * s + 1] = dy * px + dx * py + cy;
        }
    }
}

// ---------------- final pair gather -> d_out ----------------
__global__ __launch_bounds__(256) void pairs_final_kernel(
    const float* __restrict__ pt, float* __restrict__ outp, int nsegP)
{
    int npnt = nsegP * 3;
    int Pn = 2 * nsegP + 1;
    int idx = blockIdx.x * 256 + threadIdx.x;
    int total = 32 * Pn * 2;
    if (idx >= total) return;
    int c = idx & 1;
    int t = idx >> 1;
    int p = t % Pn, b = t / Pn;
    int i1, i2; pair_idx(p, Pn, npnt, i1, i2);
    float v = 0.5f * (pt[((size_t)b * npnt + i1) * 2 + c] +
                      pt[((size_t)b * npnt + i2) * 2 + c]);
    if (p < Pn - 1) outp[((size_t)b * (Pn - 1) + p) * 2 + c] = 6.f * v;
}

// ---------------- launch ----------------
extern "C" void kernel_launch(void* const* d_in, const int* in_sizes, int n_in,
                              void* d_out, int out_size, void* d_ws, size_t ws_size,
                              hipStream_t stream) {
    (void)in_sizes; (void)n_in; (void)out_size; (void)ws_size;
    const float* feats[3] = {(const float*)d_in[1], (const float*)d_in[2], (const float*)d_in[3]};

    char* ws = (char*)d_ws;
    float* predA = (float*)(ws + OFF_PRED);
    float* ptA   = (float*)(ws + OFF_PTA);
    float* ptB   = (float*)(ws + OFF_PTB);
    __hip_bfloat16* xb = (__hip_bfloat16*)(ws + OFF_X);
    float* P1          = (float*)(ws + OFF_P1);

    const int Ks[3]   = {25088, 12544, 6272};
    const int S1s[3]  = {28, 14, 7};          // slice = 896
    const int lcs[3]  = {9, 8, 7};
    const int Hs[3]   = {28, 56, 112};
    const int lnss[3] = {3, 4, 5};

    SetupArgs sa;
    size_t w1off = 0;
    for (int h = 0; h < 3; ++h) {
        sa.W1s[h] = (const float*)d_in[6 + 6 * h];
        sa.W1T[h] = (__hip_bfloat16*)(ws + OFF_W1T + w1off);
        sa.K[h]   = Ks[h];
        w1off += (size_t)Ks[h] * 1024 * 2;
        sa.W2s[h] = (const float*)d_in[8 + 6 * h];
        sa.W2B[h] = (__hip_bfloat16*)(ws + OFF_W2B + (size_t)h * 524288);
    }
    sa.lf = (const float*)d_in[0];
    sa.Wt = (const float*)d_in[4];
    sa.bt = (const float*)d_in[5];
    sa.pred = predA;

    setup_kernel<<<dim3(11888), 256, 0, stream>>>(sa);

    float* pts[2] = {ptA, ptB};
    const float* ptPrev = nullptr;
    int nsegP = 0;
    for (int h = 0; h < 3; ++h) {
        int lns = lnss[h], nseg = 1 << lns, M = 32 * nseg;
        int K = Ks[h], S1 = S1s[h];
        const float* b1 = (const float*)d_in[7 + 6 * h];
        const float* b2 = (const float*)d_in[9 + 6 * h];
        const float* W3 = (const float*)d_in[10 + 6 * h];
        const float* b3 = (const float*)d_in[11 + 6 * h];

        sample_kernel<<<dim3(32 * nseg), 256, 0, stream>>>(
            feats[h], Hs[h], lcs[h], predA, ptPrev, nsegP, lns, xb);

        gemm_mfma4<<<dim3(M / 64, 4, S1), 256, 0, stream>>>(
            xb, sa.W1T[h], P1, M, 1024, K, K / S1);

        float* ptCur = pts[h & 1];
        tail_kernel<<<dim3(M / 4), 256, 0, stream>>>(
            P1, b1, sa.W2B[h], b2, W3, b3, predA, ptPrev, nsegP,
            ptCur, lns, M, S1);

        ptPrev = ptCur; nsegP = nseg;
    }

    pairs_final_kernel<<<dim3((32 * 65 * 2 + 255) / 256), 256, 0, stream>>>(
        ptA, (float*)d_out, 32);
}